// Round 1
// baseline (596.149 us; speedup 1.0000x reference)
//
#include <hip/hip_runtime.h>
#include <stdint.h>

typedef unsigned short u16;
typedef __attribute__((ext_vector_type(4))) float f32x4;
typedef __attribute__((ext_vector_type(8))) __bf16 bf16x8;
typedef __attribute__((ext_vector_type(4))) u16 u16x4;
typedef __attribute__((ext_vector_type(8))) u16 u16x8;

#define S_LEN 2048
#define HIDDEN 4096
#define NHEAD 32
#define NKVH 8
#define HD 128
#define WIN 1024

__device__ __forceinline__ float bf2f(u16 u) {
  union { unsigned int i; float f; } x; x.i = ((unsigned int)u) << 16; return x.f;
}
__device__ __forceinline__ u16 f2bf(float f) {
  union { float f; unsigned int i; } x; x.f = f;
  unsigned int r = x.i + 0x7FFFu + ((x.i >> 16) & 1u);
  return (u16)(r >> 16);
}

__device__ __forceinline__ void gload16(const void* g, void* l) {
  __builtin_amdgcn_global_load_lds((const __attribute__((address_space(1))) void*)g,
                                   (__attribute__((address_space(3))) void*)l, 16, 0, 0);
}

// ---------------- fp32 -> bf16 convert (X) ----------------
__global__ __launch_bounds__(256) void conv_bf16_k(const float* __restrict__ in, u16* __restrict__ out) {
  size_t i = ((size_t)blockIdx.x * 256 + threadIdx.x) * 8;
  f32x4 a = *(const f32x4*)(in + i);
  f32x4 b = *(const f32x4*)(in + i + 4);
  u16x8 o;
  o[0] = f2bf(a[0]); o[1] = f2bf(a[1]); o[2] = f2bf(a[2]); o[3] = f2bf(a[3]);
  o[4] = f2bf(b[0]); o[5] = f2bf(b[1]); o[6] = f2bf(b[2]); o[7] = f2bf(b[3]);
  *(u16x8*)(out + i) = o;
}

// ---------------- bias concat ----------------
__global__ __launch_bounds__(256) void concat_bias_k(const float* __restrict__ bq, const float* __restrict__ bk,
                                                     const float* __restrict__ bv, float* __restrict__ o) {
  int i = blockIdx.x * 256 + threadIdx.x;
  float v = (i < 4096) ? bq[i] : (i < 5120 ? bk[i - 4096] : bv[i - 5120]);
  o[i] = v;
}

// ---------------- transpose (+convert) to bf16: out[c][r] = in[r][c] ----------------
// grid.x tiles rows (R/64), grid.y tiles cols (C/64). Dims are multiples of 64.
template <typename TIN>
__global__ __launch_bounds__(256) void transpose_bf16_k(const TIN* __restrict__ in, int istride,
                                                        u16* __restrict__ out, int ostride) {
  __shared__ TIN tile[64][68];
  int r0 = blockIdx.x * 64, c0 = blockIdx.y * 64;
  int t = threadIdx.x;
  int tr = t >> 4;
  int tc = (t & 15) * 4;
#pragma unroll
  for (int i = 0; i < 4; ++i) {
    int r = i * 16 + tr;
    const TIN* src = in + (size_t)(r0 + r) * istride + c0 + tc;
    if constexpr (sizeof(TIN) == 4) {
      *(f32x4*)&tile[r][tc] = *(const f32x4*)src;
    } else {
      *(u16x4*)&tile[r][tc] = *(const u16x4*)src;
    }
  }
  __syncthreads();
#pragma unroll
  for (int i = 0; i < 4; ++i) {
    int rr = i * 16 + tr;  // relative output row (= input col)
    u16x4 o;
#pragma unroll
    for (int j = 0; j < 4; ++j) {
      if constexpr (sizeof(TIN) == 4) o[j] = f2bf((float)tile[tc + j][rr]);
      else o[j] = (u16)tile[tc + j][rr];
    }
    *(u16x4*)(out + (size_t)(c0 + rr) * ostride + r0 + tc) = o;
  }
}

// ---------------- GEMM: C[M][N] = A[M][K](bf16) * Bt[N][K](bf16)^T + bias ----------------
// 128x128 tile, BK=32, 256 threads (4 waves, 2x2), each wave 64x64 = 4x4 frags of 16x16.
template <typename TOUT>
__global__ __launch_bounds__(256) void gemm_bt_k(const u16* __restrict__ A, const u16* __restrict__ Bt,
                                                 const float* __restrict__ bias, TOUT* __restrict__ C,
                                                 int M, int N, int K) {
  __shared__ u16 As[128 * 32];
  __shared__ u16 Bs[128 * 32];
  int tid = threadIdx.x;
  int w = tid >> 6, lane = tid & 63;
  int cl = lane & 15, g = lane >> 4;
  int nbm = M >> 7;
  int bm = blockIdx.x % nbm, bn = blockIdx.x / nbm;
  int wr = w >> 1, wc = w & 1;
  int ldr = lane >> 2;          // staging row within 16-row group
  int ldc = (lane & 3) * 8;     // staging k-offset (elements)

  f32x4 acc[4][4] = {};
  const u16* Abase = A + (size_t)bm * 128 * K;
  const u16* Bbase = Bt + (size_t)bn * 128 * K;

  for (int kt = 0; kt < K; kt += 32) {
#pragma unroll
    for (int i = 0; i < 2; ++i) {
      int rowbase = w * 32 + i * 16;
      gload16(Abase + (size_t)(rowbase + ldr) * K + kt + ldc, (void*)(As + rowbase * 32));
      gload16(Bbase + (size_t)(rowbase + ldr) * K + kt + ldc, (void*)(Bs + rowbase * 32));
    }
    __syncthreads();
    bf16x8 af[4], bf[4];
#pragma unroll
    for (int m = 0; m < 4; ++m) af[m] = *(const bf16x8*)(As + (wr * 64 + m * 16 + cl) * 32 + g * 8);
#pragma unroll
    for (int n = 0; n < 4; ++n) bf[n] = *(const bf16x8*)(Bs + (wc * 64 + n * 16 + cl) * 32 + g * 8);
#pragma unroll
    for (int m = 0; m < 4; ++m)
#pragma unroll
      for (int n = 0; n < 4; ++n)
        acc[m][n] = __builtin_amdgcn_mfma_f32_16x16x32_bf16(af[m], bf[n], acc[m][n], 0, 0, 0);
    __syncthreads();
  }

#pragma unroll
  for (int m = 0; m < 4; ++m) {
    int row0 = bm * 128 + wr * 64 + m * 16 + g * 4;
#pragma unroll
    for (int n = 0; n < 4; ++n) {
      int col = bn * 128 + wc * 64 + n * 16 + cl;
      float bb = bias[col];
#pragma unroll
      for (int r = 0; r < 4; ++r) {
        float v = acc[m][n][r] + bb;
        if constexpr (sizeof(TOUT) == 2) C[(size_t)(row0 + r) * N + col] = f2bf(v);
        else C[(size_t)(row0 + r) * N + col] = v;
      }
    }
  }
}

// ---------------- RoPE + scatter Q/K ----------------
// p -> (s, head-slot, d-pair). Q scaled by 1/sqrt(HD).
__global__ __launch_bounds__(256) void rope_scatter_k(const u16* __restrict__ qkv, const int* __restrict__ pos,
                                                      const float* __restrict__ cosT, const float* __restrict__ sinT,
                                                      u16* __restrict__ Q, u16* __restrict__ Kb) {
  int p = blockIdx.x * 256 + threadIdx.x;  // exactly 2048*2560 threads
  int s = p / 2560;
  int rem = p - s * 2560;
  int hs = rem >> 6;
  int d = rem & 63;
  int ps = pos[s];
  const float* cb = cosT + (size_t)ps * 128;
  const float* sb = sinT + (size_t)ps * 128;
  float c0 = cb[d], c1 = cb[d + 64], s0 = sb[d], s1 = sb[d + 64];
  if (hs < NHEAD) {
    const u16* src = qkv + (size_t)s * 6144 + hs * 128;
    float x0 = bf2f(src[d]), x1 = bf2f(src[d + 64]);
    const float qs = 0.08838834764831845f;  // 1/sqrt(128)
    u16* dst = Q + ((size_t)hs * S_LEN + s) * HD;
    dst[d] = f2bf((x0 * c0 - x1 * s0) * qs);
    dst[d + 64] = f2bf((x1 * c1 + x0 * s1) * qs);
  } else {
    int kh = hs - NHEAD;
    const u16* src = qkv + (size_t)s * 6144 + 4096 + kh * 128;
    float x0 = bf2f(src[d]), x1 = bf2f(src[d + 64]);
    u16* dst = Kb + ((size_t)kh * S_LEN + s) * HD;
    dst[d] = f2bf(x0 * c0 - x1 * s0);
    dst[d + 64] = f2bf(x1 * c1 + x0 * s1);
  }
}

// ---------------- flash attention (sliding window, GQA) ----------------
// grid = NH * (S/64). 4 waves/block; wave w owns 16 q-rows, fully independent (no barriers).
__global__ __launch_bounds__(256) void attn_k(const u16* __restrict__ Q, const u16* __restrict__ Kb,
                                              const u16* __restrict__ Vt, u16* __restrict__ O) {
  __shared__ u16 Pl[4][16 * 64];
  int w = threadIdx.x >> 6, lane = threadIdx.x & 63;
  int cl = lane & 15, g = lane >> 4;
  int h = blockIdx.x >> 5, qb = blockIdx.x & 31;
  int i0 = qb * 64 + w * 16;
  int kh = h >> 2;
  char* myP = (char*)Pl[w];

  bf16x8 qf[4];
  const u16* qbase = Q + ((size_t)h * S_LEN + i0 + cl) * HD + g * 8;
#pragma unroll
  for (int dc = 0; dc < 4; ++dc) qf[dc] = *(const bf16x8*)(qbase + dc * 32);

  f32x4 of[8] = {};
  float m_r[4] = {-1e30f, -1e30f, -1e30f, -1e30f};
  float l_r[4] = {0.f, 0.f, 0.f, 0.f};

  int jstart = (i0 > 1023) ? ((i0 - 1023) & ~63) : 0;
  for (int j0 = jstart; j0 <= i0 + 15; j0 += 64) {
    f32x4 sa[4] = {};
#pragma unroll
    for (int f = 0; f < 4; ++f) {
      const u16* kbase = Kb + ((size_t)kh * S_LEN + j0 + f * 16 + cl) * HD + g * 8;
#pragma unroll
      for (int dc = 0; dc < 4; ++dc) {
        bf16x8 kf = *(const bf16x8*)(kbase + dc * 32);
        sa[f] = __builtin_amdgcn_mfma_f32_16x16x32_bf16(qf[dc], kf, sa[f], 0, 0, 0);
      }
    }
    bool interior = (j0 + 63 <= i0) && (j0 >= i0 - 1008);
    if (!interior) {
#pragma unroll
      for (int f = 0; f < 4; ++f)
#pragma unroll
        for (int r = 0; r < 4; ++r) {
          int q = i0 + g * 4 + r;
          int kv = j0 + f * 16 + cl;
          if (kv > q || kv <= q - WIN) sa[f][r] = -1e9f;
        }
    }
#pragma unroll
    for (int r = 0; r < 4; ++r) {
      float v = fmaxf(fmaxf(sa[0][r], sa[1][r]), fmaxf(sa[2][r], sa[3][r]));
      v = fmaxf(v, __shfl_xor(v, 1));
      v = fmaxf(v, __shfl_xor(v, 2));
      v = fmaxf(v, __shfl_xor(v, 4));
      v = fmaxf(v, __shfl_xor(v, 8));
      float mnew = fmaxf(m_r[r], v);
      float sc = __expf(m_r[r] - mnew);
      m_r[r] = mnew;
      l_r[r] *= sc;
#pragma unroll
      for (int df = 0; df < 8; ++df) of[df][r] *= sc;
      float rs = 0.f;
#pragma unroll
      for (int f = 0; f < 4; ++f) {
        float pv = __expf(sa[f][r] - mnew);
        sa[f][r] = pv;
        rs += pv;
      }
      rs += __shfl_xor(rs, 1);
      rs += __shfl_xor(rs, 2);
      rs += __shfl_xor(rs, 4);
      rs += __shfl_xor(rs, 8);
      l_r[r] += rs;
    }
    // write P (bf16) to per-wave LDS, XOR-swizzled (16B chunk ^= row&7)
#pragma unroll
    for (int r = 0; r < 4; ++r) {
      int row = g * 4 + r;
      int sw = (row & 7) << 4;
#pragma unroll
      for (int f = 0; f < 4; ++f) {
        int b = row * 128 + (((f * 16 + cl) * 2) ^ sw);
        *(u16*)(myP + b) = f2bf(sa[f][r]);
      }
    }
    bf16x8 pa[2];
    {
      int row = cl;
      int sw = (row & 7) << 4;
      pa[0] = *(const bf16x8*)(myP + row * 128 + ((g * 16) ^ sw));
      pa[1] = *(const bf16x8*)(myP + row * 128 + ((64 + g * 16) ^ sw));
    }
#pragma unroll
    for (int df = 0; df < 8; ++df) {
      const u16* vb = Vt + ((size_t)kh * HD + df * 16 + cl) * S_LEN + j0 + g * 8;
      of[df] = __builtin_amdgcn_mfma_f32_16x16x32_bf16(pa[0], *(const bf16x8*)vb, of[df], 0, 0, 0);
      of[df] = __builtin_amdgcn_mfma_f32_16x16x32_bf16(pa[1], *(const bf16x8*)(vb + 32), of[df], 0, 0, 0);
    }
  }

#pragma unroll
  for (int r = 0; r < 4; ++r) {
    float inv = 1.0f / l_r[r];
    int row = i0 + g * 4 + r;
#pragma unroll
    for (int df = 0; df < 8; ++df) {
      O[(size_t)row * HIDDEN + h * HD + df * 16 + cl] = f2bf(of[df][r] * inv);
    }
  }
}

extern "C" void kernel_launch(void* const* d_in, const int* in_sizes, int n_in,
                              void* d_out, int out_size, void* d_ws, size_t ws_size,
                              hipStream_t stream) {
  const float* X = (const float*)d_in[0];
  // d_in[1] = attention_mask: sliding-window causal, computed analytically in-kernel
  const int* pos = (const int*)d_in[2];
  const float* cosT = (const float*)d_in[3];
  const float* sinT = (const float*)d_in[4];
  const float* Wq = (const float*)d_in[5];
  const float* bq = (const float*)d_in[6];
  const float* Wk = (const float*)d_in[7];
  const float* bk = (const float*)d_in[8];
  const float* Wv = (const float*)d_in[9];
  const float* bv = (const float*)d_in[10];
  const float* Wo = (const float*)d_in[11];
  const float* bo = (const float*)d_in[12];
  float* out = (float*)d_out;

  const size_t MB = 1ull << 20;
  char* ws = (char*)d_ws;
  u16* WT = (u16*)ws;                     // 48MB: Wqkv^T (bf16 [6144][4096]); later Wo^T [4096][4096]
  u16* Xb = (u16*)(ws + 48 * MB);         // 16MB: X bf16; later Q [32][2048][128]
  u16* Qs = Xb;
  u16* QKVr = (u16*)(ws + 64 * MB);       // 24MB: QKV raw [2048][6144]; later attnO [2048][4096]
  u16* attnO = QKVr;
  u16* Kb = (u16*)(ws + 88 * MB);         // 4MB: K [8][2048][128]
  u16* Vt = (u16*)(ws + 92 * MB);         // 4MB: V^T [8][128][2048]
  float* bqkv = (float*)(ws + 96 * MB);   // 24KB

  conv_bf16_k<<<4096, 256, 0, stream>>>(X, Xb);
  transpose_bf16_k<float><<<dim3(64, 64), 256, 0, stream>>>(Wq, 4096, WT, 4096);
  transpose_bf16_k<float><<<dim3(64, 16), 256, 0, stream>>>(Wk, 1024, WT + (size_t)4096 * 4096, 4096);
  transpose_bf16_k<float><<<dim3(64, 16), 256, 0, stream>>>(Wv, 1024, WT + (size_t)5120 * 4096, 4096);
  concat_bias_k<<<24, 256, 0, stream>>>(bq, bk, bv, bqkv);

  gemm_bt_k<u16><<<16 * 48, 256, 0, stream>>>(Xb, WT, bqkv, QKVr, 2048, 6144, 4096);

  rope_scatter_k<<<20480, 256, 0, stream>>>(QKVr, pos, cosT, sinT, Qs, Kb);
  transpose_bf16_k<u16><<<dim3(32, 16), 256, 0, stream>>>(QKVr + 5120, 6144, Vt, 2048);
  transpose_bf16_k<float><<<dim3(64, 64), 256, 0, stream>>>(Wo, 4096, WT, 4096);

  attn_k<<<1024, 256, 0, stream>>>(Qs, Kb, Vt, attnO);

  gemm_bt_k<float><<<16 * 32, 256, 0, stream>>>(attnO, WT, bo, out, 2048, 4096, 4096);
}

// Round 3
// 382.761 us; speedup vs baseline: 1.5575x; 1.5575x over previous
//
#include <hip/hip_runtime.h>
#include <stdint.h>

typedef unsigned short u16;
typedef __attribute__((ext_vector_type(4))) float f32x4;
typedef __attribute__((ext_vector_type(16))) float f32x16;
typedef __attribute__((ext_vector_type(8))) __bf16 bf16x8;
typedef __attribute__((ext_vector_type(4))) u16 u16x4;
typedef __attribute__((ext_vector_type(8))) u16 u16x8;
typedef __attribute__((ext_vector_type(4))) unsigned int u32x4;

#define S_LEN 2048
#define HIDDEN 4096
#define NHEAD 32
#define NKVH 8
#define HD 128
#define WIN 1024

__device__ __forceinline__ float bf2f(u16 u) {
  union { unsigned int i; float f; } x; x.i = ((unsigned int)u) << 16; return x.f;
}
__device__ __forceinline__ u16 f2bf(float f) {
  union { float f; unsigned int i; } x; x.f = f;
  unsigned int r = x.i + 0x7FFFu + ((x.i >> 16) & 1u);
  return (u16)(r >> 16);
}

__device__ __forceinline__ void gload16(const void* g, void* l) {
  __builtin_amdgcn_global_load_lds((const __attribute__((address_space(1))) void*)g,
                                   (__attribute__((address_space(3))) void*)l, 16, 0, 0);
}

__device__ __forceinline__ unsigned int cvtpk_bf16(float a, float b) {
  unsigned int w;
  asm("v_cvt_pk_bf16_f32 %0, %1, %2" : "=v"(w) : "v"(a), "v"(b));
  return w;
}

// ---------------- fp32 -> bf16 convert (X) ----------------
__global__ __launch_bounds__(256) void conv_bf16_k(const float* __restrict__ in, u16* __restrict__ out) {
  size_t i = ((size_t)blockIdx.x * 256 + threadIdx.x) * 8;
  f32x4 a = *(const f32x4*)(in + i);
  f32x4 b = *(const f32x4*)(in + i + 4);
  u16x8 o;
  o[0] = f2bf(a[0]); o[1] = f2bf(a[1]); o[2] = f2bf(a[2]); o[3] = f2bf(a[3]);
  o[4] = f2bf(b[0]); o[5] = f2bf(b[1]); o[6] = f2bf(b[2]); o[7] = f2bf(b[3]);
  *(u16x8*)(out + i) = o;
}

// ---------------- bias concat ----------------
__global__ __launch_bounds__(256) void concat_bias_k(const float* __restrict__ bq, const float* __restrict__ bk,
                                                     const float* __restrict__ bv, float* __restrict__ o) {
  int i = blockIdx.x * 256 + threadIdx.x;
  float v = (i < 4096) ? bq[i] : (i < 5120 ? bk[i - 4096] : bv[i - 5120]);
  o[i] = v;
}

// ---------------- transpose (+convert) to bf16: out[c][r] = in[r][c] ----------------
template <typename TIN>
__global__ __launch_bounds__(256) void transpose_bf16_k(const TIN* __restrict__ in, int istride,
                                                        u16* __restrict__ out, int ostride) {
  __shared__ TIN tile[64][68];
  int r0 = blockIdx.x * 64, c0 = blockIdx.y * 64;
  int t = threadIdx.x;
  int tr = t >> 4;
  int tc = (t & 15) * 4;
#pragma unroll
  for (int i = 0; i < 4; ++i) {
    int r = i * 16 + tr;
    const TIN* src = in + (size_t)(r0 + r) * istride + c0 + tc;
    if constexpr (sizeof(TIN) == 4) {
      *(f32x4*)&tile[r][tc] = *(const f32x4*)src;
    } else {
      *(u16x4*)&tile[r][tc] = *(const u16x4*)src;
    }
  }
  __syncthreads();
#pragma unroll
  for (int i = 0; i < 4; ++i) {
    int rr = i * 16 + tr;
    u16x4 o;
#pragma unroll
    for (int j = 0; j < 4; ++j) {
      if constexpr (sizeof(TIN) == 4) o[j] = f2bf((float)tile[tc + j][rr]);
      else o[j] = (u16)tile[tc + j][rr];
    }
    *(u16x4*)(out + (size_t)(c0 + rr) * ostride + r0 + tc) = o;
  }
}

// ---------------- GEMM: C[M][N] = A[M][K](bf16) * Bt[N][K](bf16)^T + bias ----------------
template <typename TOUT>
__global__ __launch_bounds__(256) void gemm_bt_k(const u16* __restrict__ A, const u16* __restrict__ Bt,
                                                 const float* __restrict__ bias, TOUT* __restrict__ C,
                                                 int M, int N, int K) {
  __shared__ u16 As[128 * 32];
  __shared__ u16 Bs[128 * 32];
  int tid = threadIdx.x;
  int w = tid >> 6, lane = tid & 63;
  int cl = lane & 15, g = lane >> 4;
  int nbm = M >> 7;
  int bm = blockIdx.x % nbm, bn = blockIdx.x / nbm;
  int wr = w >> 1, wc = w & 1;
  int ldr = lane >> 2;
  int ldc = (lane & 3) * 8;

  f32x4 acc[4][4] = {};
  const u16* Abase = A + (size_t)bm * 128 * K;
  const u16* Bbase = Bt + (size_t)bn * 128 * K;

  for (int kt = 0; kt < K; kt += 32) {
#pragma unroll
    for (int i = 0; i < 2; ++i) {
      int rowbase = w * 32 + i * 16;
      gload16(Abase + (size_t)(rowbase + ldr) * K + kt + ldc, (void*)(As + rowbase * 32));
      gload16(Bbase + (size_t)(rowbase + ldr) * K + kt + ldc, (void*)(Bs + rowbase * 32));
    }
    __syncthreads();
    bf16x8 af[4], bf[4];
#pragma unroll
    for (int m = 0; m < 4; ++m) af[m] = *(const bf16x8*)(As + (wr * 64 + m * 16 + cl) * 32 + g * 8);
#pragma unroll
    for (int n = 0; n < 4; ++n) bf[n] = *(const bf16x8*)(Bs + (wc * 64 + n * 16 + cl) * 32 + g * 8);
#pragma unroll
    for (int m = 0; m < 4; ++m)
#pragma unroll
      for (int n = 0; n < 4; ++n)
        acc[m][n] = __builtin_amdgcn_mfma_f32_16x16x32_bf16(af[m], bf[n], acc[m][n], 0, 0, 0);
    __syncthreads();
  }

#pragma unroll
  for (int m = 0; m < 4; ++m) {
    int row0 = bm * 128 + wr * 64 + m * 16 + g * 4;
#pragma unroll
    for (int n = 0; n < 4; ++n) {
      int col = bn * 128 + wc * 64 + n * 16 + cl;
      float bb = bias[col];
#pragma unroll
      for (int r = 0; r < 4; ++r) {
        float v = acc[m][n][r] + bb;
        if constexpr (sizeof(TOUT) == 2) C[(size_t)(row0 + r) * N + col] = f2bf(v);
        else C[(size_t)(row0 + r) * N + col] = v;
      }
    }
  }
}

// ---------------- RoPE + scatter Q (linear) / K (MFMA-fragment-packed) ----------------
// K elem (kh, s, d) -> Kf[((kh*64 + s/32)*8 + d/16)*512 + ((s&31) + 32*((d>>3)&1))*8 + (d&7)]
// attn lane l reading 16B at ((kh*64+t)*8+ks)*512 + l*8 gets K[t*32 + (l&31)][ks*16 + (l>>5)*8 + j].
__global__ __launch_bounds__(256) void rope_scatter_k(const u16* __restrict__ qkv, const int* __restrict__ pos,
                                                      const float* __restrict__ cosT, const float* __restrict__ sinT,
                                                      u16* __restrict__ Q, u16* __restrict__ Kf) {
  int p = blockIdx.x * 256 + threadIdx.x;
  int s = p / 2560;
  int rem = p - s * 2560;
  int hs = rem >> 6;
  int d = rem & 63;
  int ps = pos[s];
  const float* cb = cosT + (size_t)ps * 128;
  const float* sb = sinT + (size_t)ps * 128;
  float c0 = cb[d], c1 = cb[d + 64], s0 = sb[d], s1 = sb[d + 64];
  if (hs < NHEAD) {
    const u16* src = qkv + (size_t)s * 6144 + hs * 128;
    float x0 = bf2f(src[d]), x1 = bf2f(src[d + 64]);
    const float qs = 0.08838834764831845f;  // 1/sqrt(128)
    u16* dst = Q + ((size_t)hs * S_LEN + s) * HD;
    dst[d] = f2bf((x0 * c0 - x1 * s0) * qs);
    dst[d + 64] = f2bf((x1 * c1 + x0 * s1) * qs);
  } else {
    int kh = hs - NHEAD;
    const u16* src = qkv + (size_t)s * 6144 + 4096 + kh * 128;
    float x0 = bf2f(src[d]), x1 = bf2f(src[d + 64]);
    int t = s >> 5, cr = s & 31;
    int ks = d >> 4, hi2 = (d >> 3) & 1, j = d & 7;
    size_t base = ((size_t)(kh * 64 + t) * 8 + ks) * 512 + (size_t)(cr + 32 * hi2) * 8 + j;
    Kf[base] = f2bf(x0 * c0 - x1 * s0);
    Kf[base + 4 * 512] = f2bf(x1 * c1 + x0 * s1);
  }
}

// ---------------- V -> MFMA-fragment-packed layout ----------------
// Vf chunk (kh, t, dt, sl): lane l elem j = V[t*32 + sl*16 + (l>>5)*8 + j][dt*32 + (l&31)]
__global__ __launch_bounds__(256) void vfrag_k(const u16* __restrict__ qkv, u16* __restrict__ Vf) {
  __shared__ u16 tile[32][136];  // 272B rows: keeps 16B vector stores aligned (132 was the round-1 bug)
  int bid = blockIdx.x;
  int kh = bid >> 6, t = bid & 63;
  int tid = threadIdx.x;
#pragma unroll
  for (int i = 0; i < 2; ++i) {
    int c = tid + i * 256;          // 512 chunks of 16B
    int r = c >> 4, seg = c & 15;
    *(u16x8*)&tile[r][seg * 8] =
        *(const u16x8*)(qkv + (size_t)(t * 32 + r) * 6144 + 5120 + kh * 128 + seg * 8);
  }
  __syncthreads();
#pragma unroll
  for (int i = 0; i < 2; ++i) {
    int pos = tid + i * 256;        // 512 fragment-lane slots
    int dt = pos >> 7, sl = (pos >> 6) & 1, l = pos & 63;
    int c2 = l & 31, h2 = l >> 5;
    u16x8 o;
#pragma unroll
    for (int j = 0; j < 8; ++j) o[j] = tile[sl * 16 + h2 * 8 + j][dt * 32 + c2];
    *(u16x8*)(Vf + ((size_t)(kh * 512 + t * 8 + dt * 2 + sl)) * 512 + (size_t)l * 8) = o;
  }
}

// ---------------- flash attention: swapped-QK^T 32x32, in-register softmax ----------------
// grid 512: bid&7 = kv-head (XCD colocation), 4 waves x 32 q-rows each, KVBLK=32, no LDS/barriers.
__global__ __launch_bounds__(256, 2) void attn_k(const u16* __restrict__ Q, const u16* __restrict__ Kf,
                                                 const u16* __restrict__ Vf, u16* __restrict__ O) {
  int l = threadIdx.x & 63, w = threadIdx.x >> 6;
  int col = l & 31, hi = l >> 5;
  int bid = blockIdx.x;
  int kh = bid & 7;
  int rest = bid >> 3;
  int h = kh * 4 + (rest & 3);
  int q0 = (rest >> 2) * 128 + w * 32;

  // Q as B-operand: lane l holds Q[q0 + (l&31)][ks*16 + (l>>5)*8 + j]
  bf16x8 qf[8];
  const u16* qbase = Q + ((size_t)h * S_LEN + q0 + col) * HD + hi * 8;
#pragma unroll
  for (int ks = 0; ks < 8; ++ks) qf[ks] = *(const bf16x8*)(qbase + ks * 16);

  f32x16 ot[4];
#pragma unroll
  for (int dt = 0; dt < 4; ++dt)
#pragma unroll
    for (int r = 0; r < 16; ++r) ot[dt][r] = 0.f;
  float m_r = -3.0e38f, l_r = 0.f;

  const u16* kf0 = Kf + (size_t)kh * 64 * 4096 + (size_t)l * 8;
  const u16* vf0 = Vf + (size_t)kh * 512 * 512 + (size_t)l * 8;

  int jstart = q0 >= WIN ? q0 - WIN : 0;
  for (int j0 = jstart; j0 <= q0; j0 += 32) {
    int t = j0 >> 5;
    const u16* kb = kf0 + (size_t)t * 4096;
    bf16x8 kfr[8];
#pragma unroll
    for (int ks = 0; ks < 8; ++ks) kfr[ks] = *(const bf16x8*)(kb + ks * 512);
    // S^T = K * Q^T : D[kv][q], col=lane&31=q, row=(r&3)+8*(r>>2)+4*hi
    f32x16 s = {};
#pragma unroll
    for (int ks = 0; ks < 8; ++ks)
      s = __builtin_amdgcn_mfma_f32_32x32x16_bf16(kfr[ks], qf[ks], s, 0, 0, 0);
    // V fragments issued early (latency hides under softmax)
    const u16* vb = vf0 + (size_t)t * 4096;
    bf16x8 vfr[8];
#pragma unroll
    for (int c = 0; c < 8; ++c) vfr[c] = *(const bf16x8*)(vb + c * 512);

    // sliding-window causal mask (only boundary tiles need it)
    if (j0 + 31 > q0 || j0 < q0 - 992) {
      int q = q0 + col;
#pragma unroll
      for (int r = 0; r < 16; ++r) {
        int kv = j0 + (r & 3) + 8 * (r >> 2) + 4 * hi;
        if (kv > q || kv <= q - WIN) s[r] = -3.0e38f;  // self-heals via exp(-inf)=0 rescale
      }
    }
    // row max: 15 in-register fmax + cross-half merge (shfl_xor 32: semantics-safe)
    float vm = fmaxf(fmaxf(fmaxf(s[0], s[1]), fmaxf(s[2], s[3])),
                     fmaxf(fmaxf(s[4], s[5]), fmaxf(s[6], s[7])));
    vm = fmaxf(vm, fmaxf(fmaxf(fmaxf(s[8], s[9]), fmaxf(s[10], s[11])),
                         fmaxf(fmaxf(s[12], s[13]), fmaxf(s[14], s[15]))));
    vm = fmaxf(vm, __shfl_xor(vm, 32));
    float mnew = fmaxf(m_r, vm);
    float sc = __expf(m_r - mnew);
    m_r = mnew;
    float rs = 0.f;
#pragma unroll
    for (int r = 0; r < 16; ++r) {
      float pv = __expf(s[r] - mnew);
      s[r] = pv;
      rs += pv;
    }
    rs += __shfl_xor(rs, 32);
    l_r = l_r * sc + rs;
#pragma unroll
    for (int dt = 0; dt < 4; ++dt)
#pragma unroll
      for (int r = 0; r < 16; ++r) ot[dt][r] *= sc;

    // P^T B-fragments via cvt_pk + permlane32_swap (T12).
    // v_permlane32_swap_b32 vdst, vsrc: vdst.hi <-> vsrc.lo  (verified vs guide's recipe)
    bf16x8 pb[2];
#pragma unroll
    for (int sl = 0; sl < 2; ++sl) {
      int b = sl * 8;
      unsigned int a0 = cvtpk_bf16(s[b + 0], s[b + 1]);
      unsigned int c0 = cvtpk_bf16(s[b + 4], s[b + 5]);
      asm("v_permlane32_swap_b32 %0, %1" : "+v"(a0), "+v"(c0));
      unsigned int a1 = cvtpk_bf16(s[b + 2], s[b + 3]);
      unsigned int c1 = cvtpk_bf16(s[b + 6], s[b + 7]);
      asm("v_permlane32_swap_b32 %0, %1" : "+v"(a1), "+v"(c1));
      u32x4 pv = {a0, a1, c0, c1};
      pb[sl] = __builtin_bit_cast(bf16x8, pv);
    }
    // O^T = V^T * P^T
#pragma unroll
    for (int dt = 0; dt < 4; ++dt) {
      ot[dt] = __builtin_amdgcn_mfma_f32_32x32x16_bf16(vfr[dt * 2 + 0], pb[0], ot[dt], 0, 0, 0);
      ot[dt] = __builtin_amdgcn_mfma_f32_32x32x16_bf16(vfr[dt * 2 + 1], pb[1], ot[dt], 0, 0, 0);
    }
  }

  float inv = 1.0f / l_r;
#pragma unroll
  for (int dt = 0; dt < 4; ++dt) {
#pragma unroll
    for (int g2 = 0; g2 < 4; ++g2) {
      u16x4 o;
#pragma unroll
      for (int i = 0; i < 4; ++i) o[i] = f2bf(ot[dt][g2 * 4 + i] * inv);
      *(u16x4*)(O + (size_t)(q0 + col) * HIDDEN + h * HD + dt * 32 + g2 * 8 + hi * 4) = o;
    }
  }
}

extern "C" void kernel_launch(void* const* d_in, const int* in_sizes, int n_in,
                              void* d_out, int out_size, void* d_ws, size_t ws_size,
                              hipStream_t stream) {
  const float* X = (const float*)d_in[0];
  const int* pos = (const int*)d_in[2];
  const float* cosT = (const float*)d_in[3];
  const float* sinT = (const float*)d_in[4];
  const float* Wq = (const float*)d_in[5];
  const float* bq = (const float*)d_in[6];
  const float* Wk = (const float*)d_in[7];
  const float* bk = (const float*)d_in[8];
  const float* Wv = (const float*)d_in[9];
  const float* bv = (const float*)d_in[10];
  const float* Wo = (const float*)d_in[11];
  const float* bo = (const float*)d_in[12];
  float* out = (float*)d_out;

  const size_t MB = 1ull << 20;
  char* ws = (char*)d_ws;
  u16* WT = (u16*)ws;                     // 48MB: Wqkv^T bf16; later Wo^T
  u16* Xb = (u16*)(ws + 48 * MB);         // 16MB: X bf16; later Q [32][2048][128]
  u16* Qs = Xb;
  u16* QKVr = (u16*)(ws + 64 * MB);       // 24MB: QKV raw [2048][6144]; later attnO [2048][4096]
  u16* attnO = QKVr;
  u16* Kfr = (u16*)(ws + 88 * MB);        // 4MB: K fragment-packed
  u16* Vfr = (u16*)(ws + 92 * MB);        // 4MB: V fragment-packed
  float* bqkv = (float*)(ws + 96 * MB);   // 24KB

  conv_bf16_k<<<4096, 256, 0, stream>>>(X, Xb);
  transpose_bf16_k<float><<<dim3(64, 64), 256, 0, stream>>>(Wq, 4096, WT, 4096);
  transpose_bf16_k<float><<<dim3(64, 16), 256, 0, stream>>>(Wk, 1024, WT + (size_t)4096 * 4096, 4096);
  transpose_bf16_k<float><<<dim3(64, 16), 256, 0, stream>>>(Wv, 1024, WT + (size_t)5120 * 4096, 4096);
  concat_bias_k<<<24, 256, 0, stream>>>(bq, bk, bv, bqkv);

  gemm_bt_k<u16><<<16 * 48, 256, 0, stream>>>(Xb, WT, bqkv, QKVr, 2048, 6144, 4096);

  rope_scatter_k<<<20480, 256, 0, stream>>>(QKVr, pos, cosT, sinT, Qs, Kfr);
  vfrag_k<<<512, 256, 0, stream>>>(QKVr, Vfr);
  transpose_bf16_k<float><<<dim3(64, 64), 256, 0, stream>>>(Wo, 4096, WT, 4096);

  attn_k<<<512, 256, 0, stream>>>(Qs, Kfr, Vfr, attnO);

  gemm_bt_k<float><<<16 * 32, 256, 0, stream>>>(attnO, WT, bo, out, 2048, 4096, 4096);
}